// Round 4
// baseline (1001.897 us; speedup 1.0000x reference)
//
#include <hip/hip_runtime.h>
#include <math.h>

#define WSZ 11
#define PAD 5
#define TX 32
#define TY 24
#define IY (TY + 2*PAD)      // 34
#define RX 8
#define SSTR (TX + 2)        // 34: even (8B-aligned b64 writes), (2y+ox)%32 covers all banks
#define RY 3                 // output rows per thread in v-pass (8 groups x 3 = 24)
#define SEG (RX + 2*PAD)     // 18 floats per h-pass thread segment

struct W11 { float w[WSZ]; };

__global__ __launch_bounds__(256, 7) void ssim_l1_kernel(
    const float* __restrict__ pred, const float* __restrict__ targ,
    W11 wt, double* __restrict__ acc)
{
    constexpr int H = 2160, W = 3840;
    __shared__ float sH[5][IY][SSTR];   // h-conv of p, t, p^2, t^2, p*t  (22.6 KB)

    const int c   = blockIdx.z;
    const int gx0 = blockIdx.x * TX;
    const int gy0 = blockIdx.y * TY;
    const size_t plane = (size_t)H * W;
    const float* p = pred + (size_t)c * plane;
    const float* t = targ + (size_t)c * plane;

    const int tid = threadIdx.x;
    float l1_acc = 0.f;

    // ================= Phase A: horizontal 11-tap, global -> LDS ===========
    // thread -> (row r in [0,IY), x-chunk lx in [0,4)); threads 136..255 idle here
    {
        const int r  = tid >> 2;
        const int lx = tid & 3;
        if (r < IY) {
            const int gy  = gy0 + r - PAD;
            const int gxs = gx0 + lx * RX - PAD;      // segment start (SEG floats)
            const bool rowok = (gy >= 0) && (gy < H);

            float pv[SEG], tv[SEG];
            if (rowok && blockIdx.x >= 1 && blockIdx.x <= (W / TX) - 2) {
                // fast path: gxs-3 = gx0 + lx*8 - 8 is 32B-aligned
                const float4* p4 = (const float4*)(p + (size_t)gy * W + (gxs - 3));
                const float4* t4 = (const float4*)(t + (size_t)gy * W + (gxs - 3));
                float pb[24], tb[24];
                #pragma unroll
                for (int i = 0; i < 6; ++i) {
                    float4 a = p4[i];
                    pb[4*i+0] = a.x; pb[4*i+1] = a.y; pb[4*i+2] = a.z; pb[4*i+3] = a.w;
                    float4 b = t4[i];
                    tb[4*i+0] = b.x; tb[4*i+1] = b.y; tb[4*i+2] = b.z; tb[4*i+3] = b.w;
                }
                #pragma unroll
                for (int e = 0; e < SEG; ++e) { pv[e] = pb[e+3]; tv[e] = tb[e+3]; }
            } else if (rowok) {
                // x-edge block: guarded scalar loads
                const size_t rowoff = (size_t)gy * W;
                #pragma unroll
                for (int e = 0; e < SEG; ++e) {
                    int gx = gxs + e;
                    bool ok = (gx >= 0) && (gx < W);
                    pv[e] = ok ? p[rowoff + gx] : 0.f;
                    tv[e] = ok ? t[rowoff + gx] : 0.f;
                }
            } else {
                #pragma unroll
                for (int e = 0; e < SEG; ++e) { pv[e] = 0.f; tv[e] = 0.f; }
            }

            // e-outer / j-inner: only the 40 accumulators stay live
            float hp[RX], ht[RX], hpp[RX], htt[RX], hpt[RX];
            #pragma unroll
            for (int j = 0; j < RX; ++j) {
                hp[j] = 0.f; ht[j] = 0.f; hpp[j] = 0.f; htt[j] = 0.f; hpt[j] = 0.f;
            }
            #pragma unroll
            for (int e = 0; e < SEG; ++e) {
                float pe = pv[e], te = tv[e];
                float pp = pe * pe, tt = te * te, pt = pe * te;
                #pragma unroll
                for (int j = 0; j < RX; ++j) {
                    int k = e - j;
                    if (k >= 0 && k < WSZ) {
                        float wv = wt.w[k];
                        hp[j]  += wv * pe;
                        ht[j]  += wv * te;
                        hpp[j] += wv * pp;
                        htt[j] += wv * tt;
                        hpt[j] += wv * pt;
                    }
                }
            }
            // vectorized LDS writes: 8B-aligned (xb even, SSTR even)
            const int xb = lx * RX;
            #pragma unroll
            for (int j = 0; j < RX; j += 2) {
                *(float2*)&sH[0][r][xb + j] = make_float2(hp[j],  hp[j+1]);
                *(float2*)&sH[1][r][xb + j] = make_float2(ht[j],  ht[j+1]);
                *(float2*)&sH[2][r][xb + j] = make_float2(hpp[j], hpp[j+1]);
                *(float2*)&sH[3][r][xb + j] = make_float2(htt[j], htt[j+1]);
                *(float2*)&sH[4][r][xb + j] = make_float2(hpt[j], hpt[j+1]);
            }
            // L1 over the pixels this block owns (each staged exactly once)
            if (r >= PAD && r < PAD + TY) {
                #pragma unroll
                for (int e = PAD; e < PAD + RX; ++e)
                    l1_acc += fabsf(pv[e] - tv[e]);
            }
        }
    }
    __syncthreads();

    // ================= Phase B: vertical 11-tap + SSIM ======================
    // k-outer / j-inner: each LDS value read exactly once, 15 accumulators.
    const float C1v = 0.0001f, C2v = 0.0009f;
    float ssim_acc = 0.f;
    {
        const int ox  = tid & 31;
        const int oy0 = (tid >> 5) * RY;
        float mu1[RY], mu2[RY], spp[RY], stt[RY], spt[RY];
        #pragma unroll
        for (int j = 0; j < RY; ++j) {
            mu1[j] = 0.f; mu2[j] = 0.f; spp[j] = 0.f; stt[j] = 0.f; spt[j] = 0.f;
        }
        #pragma unroll
        for (int k = 0; k < RY + 2 * PAD; ++k) {
            float a0 = sH[0][oy0 + k][ox];
            float a1 = sH[1][oy0 + k][ox];
            float a2 = sH[2][oy0 + k][ox];
            float a3 = sH[3][oy0 + k][ox];
            float a4 = sH[4][oy0 + k][ox];
            #pragma unroll
            for (int j = 0; j < RY; ++j) {
                int kk = k - j;
                if (kk >= 0 && kk < WSZ) {
                    float wv = wt.w[kk];
                    mu1[j] += wv * a0;
                    mu2[j] += wv * a1;
                    spp[j] += wv * a2;
                    stt[j] += wv * a3;
                    spt[j] += wv * a4;
                }
            }
        }
        #pragma unroll
        for (int j = 0; j < RY; ++j) {
            float m1 = mu1[j], m2 = mu2[j];
            float mu1s = m1 * m1;
            float mu2s = m2 * m2;
            float m12  = m1 * m2;
            float num = (2.f * m12 + C1v) * (2.f * (spt[j] - m12) + C2v);
            float den = (mu1s + mu2s + C1v) * ((spp[j] - mu1s) + (stt[j] - mu2s) + C2v);
            ssim_acc += num * __builtin_amdgcn_rcpf(den);
        }
    }

    // ================= block reduction -> global double atomics =============
    #pragma unroll
    for (int off = 32; off > 0; off >>= 1) {
        ssim_acc += __shfl_down(ssim_acc, off, 64);
        l1_acc   += __shfl_down(l1_acc,   off, 64);
    }
    __shared__ float red[2][4];
    int lane = tid & 63;
    int wid  = tid >> 6;
    if (lane == 0) { red[0][wid] = ssim_acc; red[1][wid] = l1_acc; }
    __syncthreads();
    if (tid == 0) {
        float s = red[0][0] + red[0][1] + red[0][2] + red[0][3];
        float l = red[1][0] + red[1][1] + red[1][2] + red[1][3];
        atomicAdd(&acc[0], (double)s);
        atomicAdd(&acc[1], (double)l);
    }
}

__global__ void finalize_kernel(const double* __restrict__ acc,
                                float* __restrict__ out, double invN)
{
    double ssim_mean = acc[0] * invN;
    double l1_mean   = acc[1] * invN;
    out[0] = (float)(0.8 * l1_mean + 0.2 * (1.0 - ssim_mean));
}

extern "C" void kernel_launch(void* const* d_in, const int* in_sizes, int n_in,
                              void* d_out, int out_size, void* d_ws, size_t ws_size,
                              hipStream_t stream)
{
    const float* pred = (const float*)d_in[0];
    const float* targ = (const float*)d_in[1];
    float* out = (float*)d_out;
    double* acc = (double*)d_ws;

    const int C = 3, H = 2160, W = 3840;

    hipMemsetAsync(acc, 0, 2 * sizeof(double), stream);

    W11 wt;
    double g[WSZ], s = 0.0;
    for (int i = 0; i < WSZ; ++i) {
        double d = (double)i - (WSZ / 2);
        g[i] = exp(-(d * d) / (2.0 * 1.5 * 1.5));
        s += g[i];
    }
    for (int i = 0; i < WSZ; ++i) wt.w[i] = (float)(g[i] / s);

    dim3 grid(W / TX, H / TY, C);   // 120 x 90 x 3
    ssim_l1_kernel<<<grid, 256, 0, stream>>>(pred, targ, wt, acc);

    double invN = 1.0 / ((double)C * (double)H * (double)W);
    finalize_kernel<<<1, 1, 0, stream>>>(acc, out, invN);
}

// Round 5
// 979.312 us; speedup vs baseline: 1.0231x; 1.0231x over previous
//
#include <hip/hip_runtime.h>
#include <math.h>

#define WSZ 11
#define PAD 5
#define TX 32
#define TY 24
#define IY (TY + 2*PAD)      // 34
#define RX 8
#define SSTR (TX + 2)        // 34: even (8B-aligned b64 writes), (2y+ox)%32 covers all banks
#define RY 3                 // output rows per thread in v-pass (8 groups x 3 = 24)
#define SEG (RX + 2*PAD)     // 18 floats per h-pass thread segment

struct W11 { float w[WSZ]; };

// (256,6): VGPR cap ~85 — R4's (256,7) forced 36 VGPRs and spilled ~1.9GB to scratch
__global__ __launch_bounds__(256, 6) void ssim_l1_kernel(
    const float* __restrict__ pred, const float* __restrict__ targ,
    W11 wt, double* __restrict__ acc)
{
    constexpr int H = 2160, W = 3840;
    __shared__ float sH[5][IY][SSTR];   // h-conv of p, t, p^2, t^2, p*t  (22.6 KB)

    const int c   = blockIdx.z;
    const int gx0 = blockIdx.x * TX;
    const int gy0 = blockIdx.y * TY;
    const size_t plane = (size_t)H * W;
    const float* p = pred + (size_t)c * plane;
    const float* t = targ + (size_t)c * plane;

    const int tid = threadIdx.x;
    float l1_acc = 0.f;

    // ================= Phase A: horizontal 11-tap, global -> LDS ===========
    // thread -> (row r in [0,IY), x-chunk lx in [0,4)); threads 136..255 idle here
    {
        const int r  = tid >> 2;
        const int lx = tid & 3;
        if (r < IY) {
            const int gy  = gy0 + r - PAD;
            const int gxs = gx0 + lx * RX - PAD;      // segment start (SEG floats)
            const bool rowok = (gy >= 0) && (gy < H);

            float pv[SEG], tv[SEG];
            if (rowok && blockIdx.x >= 1 && blockIdx.x <= (W / TX) - 2) {
                // fast path: gxs-3 = gx0 + lx*8 - 8 is 32B-aligned
                const float4* p4 = (const float4*)(p + (size_t)gy * W + (gxs - 3));
                const float4* t4 = (const float4*)(t + (size_t)gy * W + (gxs - 3));
                float pb[24], tb[24];
                #pragma unroll
                for (int i = 0; i < 6; ++i) {
                    float4 a = p4[i];
                    pb[4*i+0] = a.x; pb[4*i+1] = a.y; pb[4*i+2] = a.z; pb[4*i+3] = a.w;
                    float4 b = t4[i];
                    tb[4*i+0] = b.x; tb[4*i+1] = b.y; tb[4*i+2] = b.z; tb[4*i+3] = b.w;
                }
                #pragma unroll
                for (int e = 0; e < SEG; ++e) { pv[e] = pb[e+3]; tv[e] = tb[e+3]; }
            } else if (rowok) {
                // x-edge block: guarded scalar loads
                const size_t rowoff = (size_t)gy * W;
                #pragma unroll
                for (int e = 0; e < SEG; ++e) {
                    int gx = gxs + e;
                    bool ok = (gx >= 0) && (gx < W);
                    pv[e] = ok ? p[rowoff + gx] : 0.f;
                    tv[e] = ok ? t[rowoff + gx] : 0.f;
                }
            } else {
                #pragma unroll
                for (int e = 0; e < SEG; ++e) { pv[e] = 0.f; tv[e] = 0.f; }
            }

            // e-outer / j-inner: only the 40 accumulators stay live
            float hp[RX], ht[RX], hpp[RX], htt[RX], hpt[RX];
            #pragma unroll
            for (int j = 0; j < RX; ++j) {
                hp[j] = 0.f; ht[j] = 0.f; hpp[j] = 0.f; htt[j] = 0.f; hpt[j] = 0.f;
            }
            #pragma unroll
            for (int e = 0; e < SEG; ++e) {
                float pe = pv[e], te = tv[e];
                float pp = pe * pe, tt = te * te, pt = pe * te;
                #pragma unroll
                for (int j = 0; j < RX; ++j) {
                    int k = e - j;
                    if (k >= 0 && k < WSZ) {
                        float wv = wt.w[k];
                        hp[j]  += wv * pe;
                        ht[j]  += wv * te;
                        hpp[j] += wv * pp;
                        htt[j] += wv * tt;
                        hpt[j] += wv * pt;
                    }
                }
            }
            // vectorized LDS writes: 8B-aligned (xb even, SSTR even)
            const int xb = lx * RX;
            #pragma unroll
            for (int j = 0; j < RX; j += 2) {
                *(float2*)&sH[0][r][xb + j] = make_float2(hp[j],  hp[j+1]);
                *(float2*)&sH[1][r][xb + j] = make_float2(ht[j],  ht[j+1]);
                *(float2*)&sH[2][r][xb + j] = make_float2(hpp[j], hpp[j+1]);
                *(float2*)&sH[3][r][xb + j] = make_float2(htt[j], htt[j+1]);
                *(float2*)&sH[4][r][xb + j] = make_float2(hpt[j], hpt[j+1]);
            }
            // L1 over the pixels this block owns (each staged exactly once)
            if (r >= PAD && r < PAD + TY) {
                #pragma unroll
                for (int e = PAD; e < PAD + RX; ++e)
                    l1_acc += fabsf(pv[e] - tv[e]);
            }
        }
    }
    __syncthreads();

    // ================= Phase B: vertical 11-tap + SSIM ======================
    // k-outer / j-inner: each LDS value read exactly once, 15 accumulators.
    const float C1v = 0.0001f, C2v = 0.0009f;
    float ssim_acc = 0.f;
    {
        const int ox  = tid & 31;
        const int oy0 = (tid >> 5) * RY;
        float mu1[RY], mu2[RY], spp[RY], stt[RY], spt[RY];
        #pragma unroll
        for (int j = 0; j < RY; ++j) {
            mu1[j] = 0.f; mu2[j] = 0.f; spp[j] = 0.f; stt[j] = 0.f; spt[j] = 0.f;
        }
        #pragma unroll
        for (int k = 0; k < RY + 2 * PAD; ++k) {
            float a0 = sH[0][oy0 + k][ox];
            float a1 = sH[1][oy0 + k][ox];
            float a2 = sH[2][oy0 + k][ox];
            float a3 = sH[3][oy0 + k][ox];
            float a4 = sH[4][oy0 + k][ox];
            #pragma unroll
            for (int j = 0; j < RY; ++j) {
                int kk = k - j;
                if (kk >= 0 && kk < WSZ) {
                    float wv = wt.w[kk];
                    mu1[j] += wv * a0;
                    mu2[j] += wv * a1;
                    spp[j] += wv * a2;
                    stt[j] += wv * a3;
                    spt[j] += wv * a4;
                }
            }
        }
        #pragma unroll
        for (int j = 0; j < RY; ++j) {
            float m1 = mu1[j], m2 = mu2[j];
            float mu1s = m1 * m1;
            float mu2s = m2 * m2;
            float m12  = m1 * m2;
            float num = (2.f * m12 + C1v) * (2.f * (spt[j] - m12) + C2v);
            float den = (mu1s + mu2s + C1v) * ((spp[j] - mu1s) + (stt[j] - mu2s) + C2v);
            ssim_acc += num * __builtin_amdgcn_rcpf(den);
        }
    }

    // ================= block reduction -> global double atomics =============
    #pragma unroll
    for (int off = 32; off > 0; off >>= 1) {
        ssim_acc += __shfl_down(ssim_acc, off, 64);
        l1_acc   += __shfl_down(l1_acc,   off, 64);
    }
    __shared__ float red[2][4];
    int lane = tid & 63;
    int wid  = tid >> 6;
    if (lane == 0) { red[0][wid] = ssim_acc; red[1][wid] = l1_acc; }
    __syncthreads();
    if (tid == 0) {
        float s = red[0][0] + red[0][1] + red[0][2] + red[0][3];
        float l = red[1][0] + red[1][1] + red[1][2] + red[1][3];
        atomicAdd(&acc[0], (double)s);
        atomicAdd(&acc[1], (double)l);
    }
}

__global__ void finalize_kernel(const double* __restrict__ acc,
                                float* __restrict__ out, double invN)
{
    double ssim_mean = acc[0] * invN;
    double l1_mean   = acc[1] * invN;
    out[0] = (float)(0.8 * l1_mean + 0.2 * (1.0 - ssim_mean));
}

extern "C" void kernel_launch(void* const* d_in, const int* in_sizes, int n_in,
                              void* d_out, int out_size, void* d_ws, size_t ws_size,
                              hipStream_t stream)
{
    const float* pred = (const float*)d_in[0];
    const float* targ = (const float*)d_in[1];
    float* out = (float*)d_out;
    double* acc = (double*)d_ws;

    const int C = 3, H = 2160, W = 3840;

    hipMemsetAsync(acc, 0, 2 * sizeof(double), stream);

    W11 wt;
    double g[WSZ], s = 0.0;
    for (int i = 0; i < WSZ; ++i) {
        double d = (double)i - (WSZ / 2);
        g[i] = exp(-(d * d) / (2.0 * 1.5 * 1.5));
        s += g[i];
    }
    for (int i = 0; i < WSZ; ++i) wt.w[i] = (float)(g[i] / s);

    dim3 grid(W / TX, H / TY, C);   // 120 x 90 x 3
    ssim_l1_kernel<<<grid, 256, 0, stream>>>(pred, targ, wt, acc);

    double invN = 1.0 / ((double)C * (double)H * (double)W);
    finalize_kernel<<<1, 1, 0, stream>>>(acc, out, invN);
}

// Round 6
// 935.220 us; speedup vs baseline: 1.0713x; 1.0471x over previous
//
#include <hip/hip_runtime.h>
#include <math.h>

#define WSZ 11
#define PAD 5
#define TX 32
#define TY 24
#define IY (TY + 2*PAD)      // 34
#define RX 8
#define SSTR (TX + 2)        // 34: even (8B-aligned b64 writes), (2y+ox)%32 covers all banks
#define RY 3                 // output rows per thread in v-pass (8 groups x 3 = 24)
#define SEG (RX + 2*PAD)     // 18 floats per h-pass thread segment

struct W11 { float w[WSZ]; };

// (256,4): cap 128 VGPR — the proven no-spill point (R3: VGPR=64, WRITE 1MB).
// (256,6)/(256,7) demoted the staging arrays to scratch: 1.7-1.9 GB spill traffic.
// Occupancy is now LDS-bound: 22.6KB -> 6 blocks/CU = 24 waves/CU.
__global__ __launch_bounds__(256, 4) void ssim_l1_kernel(
    const float* __restrict__ pred, const float* __restrict__ targ,
    W11 wt, double* __restrict__ acc)
{
    constexpr int H = 2160, W = 3840;
    __shared__ float sH[5][IY][SSTR];   // h-conv of p, t, p^2, t^2, p*t  (22.6 KB)

    const int c   = blockIdx.z;
    const int gx0 = blockIdx.x * TX;
    const int gy0 = blockIdx.y * TY;
    const size_t plane = (size_t)H * W;
    const float* p = pred + (size_t)c * plane;
    const float* t = targ + (size_t)c * plane;

    const int tid = threadIdx.x;
    float l1_acc = 0.f;

    // ================= Phase A: horizontal 11-tap, global -> LDS ===========
    // thread -> (row r in [0,IY), x-chunk lx in [0,4)); threads 136..255 idle here
    {
        const int r  = tid >> 2;
        const int lx = tid & 3;
        if (r < IY) {
            const int gy  = gy0 + r - PAD;
            const int gxs = gx0 + lx * RX - PAD;      // segment start (SEG floats)
            const bool rowok = (gy >= 0) && (gy < H);

            float pv[SEG], tv[SEG];
            if (rowok && blockIdx.x >= 1 && blockIdx.x <= (W / TX) - 2) {
                // fast path: gxs-3 = gx0 + lx*8 - 8 is 32B-aligned
                const float4* p4 = (const float4*)(p + (size_t)gy * W + (gxs - 3));
                const float4* t4 = (const float4*)(t + (size_t)gy * W + (gxs - 3));
                float pb[24], tb[24];
                #pragma unroll
                for (int i = 0; i < 6; ++i) {
                    float4 a = p4[i];
                    pb[4*i+0] = a.x; pb[4*i+1] = a.y; pb[4*i+2] = a.z; pb[4*i+3] = a.w;
                    float4 b = t4[i];
                    tb[4*i+0] = b.x; tb[4*i+1] = b.y; tb[4*i+2] = b.z; tb[4*i+3] = b.w;
                }
                #pragma unroll
                for (int e = 0; e < SEG; ++e) { pv[e] = pb[e+3]; tv[e] = tb[e+3]; }
            } else if (rowok) {
                // x-edge block: guarded scalar loads
                const size_t rowoff = (size_t)gy * W;
                #pragma unroll
                for (int e = 0; e < SEG; ++e) {
                    int gx = gxs + e;
                    bool ok = (gx >= 0) && (gx < W);
                    pv[e] = ok ? p[rowoff + gx] : 0.f;
                    tv[e] = ok ? t[rowoff + gx] : 0.f;
                }
            } else {
                #pragma unroll
                for (int e = 0; e < SEG; ++e) { pv[e] = 0.f; tv[e] = 0.f; }
            }

            // e-outer / j-inner: only the 40 accumulators stay live
            float hp[RX], ht[RX], hpp[RX], htt[RX], hpt[RX];
            #pragma unroll
            for (int j = 0; j < RX; ++j) {
                hp[j] = 0.f; ht[j] = 0.f; hpp[j] = 0.f; htt[j] = 0.f; hpt[j] = 0.f;
            }
            #pragma unroll
            for (int e = 0; e < SEG; ++e) {
                float pe = pv[e], te = tv[e];
                float pp = pe * pe, tt = te * te, pt = pe * te;
                #pragma unroll
                for (int j = 0; j < RX; ++j) {
                    int k = e - j;
                    if (k >= 0 && k < WSZ) {
                        float wv = wt.w[k];
                        hp[j]  += wv * pe;
                        ht[j]  += wv * te;
                        hpp[j] += wv * pp;
                        htt[j] += wv * tt;
                        hpt[j] += wv * pt;
                    }
                }
            }
            // vectorized LDS writes: 8B-aligned (xb even, SSTR even)
            const int xb = lx * RX;
            #pragma unroll
            for (int j = 0; j < RX; j += 2) {
                *(float2*)&sH[0][r][xb + j] = make_float2(hp[j],  hp[j+1]);
                *(float2*)&sH[1][r][xb + j] = make_float2(ht[j],  ht[j+1]);
                *(float2*)&sH[2][r][xb + j] = make_float2(hpp[j], hpp[j+1]);
                *(float2*)&sH[3][r][xb + j] = make_float2(htt[j], htt[j+1]);
                *(float2*)&sH[4][r][xb + j] = make_float2(hpt[j], hpt[j+1]);
            }
            // L1 over the pixels this block owns (each staged exactly once)
            if (r >= PAD && r < PAD + TY) {
                #pragma unroll
                for (int e = PAD; e < PAD + RX; ++e)
                    l1_acc += fabsf(pv[e] - tv[e]);
            }
        }
    }
    __syncthreads();

    // ================= Phase B: vertical 11-tap + SSIM ======================
    // k-outer / j-inner: each LDS value read exactly once, 15 accumulators.
    const float C1v = 0.0001f, C2v = 0.0009f;
    float ssim_acc = 0.f;
    {
        const int ox  = tid & 31;
        const int oy0 = (tid >> 5) * RY;
        float mu1[RY], mu2[RY], spp[RY], stt[RY], spt[RY];
        #pragma unroll
        for (int j = 0; j < RY; ++j) {
            mu1[j] = 0.f; mu2[j] = 0.f; spp[j] = 0.f; stt[j] = 0.f; spt[j] = 0.f;
        }
        #pragma unroll
        for (int k = 0; k < RY + 2 * PAD; ++k) {
            float a0 = sH[0][oy0 + k][ox];
            float a1 = sH[1][oy0 + k][ox];
            float a2 = sH[2][oy0 + k][ox];
            float a3 = sH[3][oy0 + k][ox];
            float a4 = sH[4][oy0 + k][ox];
            #pragma unroll
            for (int j = 0; j < RY; ++j) {
                int kk = k - j;
                if (kk >= 0 && kk < WSZ) {
                    float wv = wt.w[kk];
                    mu1[j] += wv * a0;
                    mu2[j] += wv * a1;
                    spp[j] += wv * a2;
                    stt[j] += wv * a3;
                    spt[j] += wv * a4;
                }
            }
        }
        #pragma unroll
        for (int j = 0; j < RY; ++j) {
            float m1 = mu1[j], m2 = mu2[j];
            float mu1s = m1 * m1;
            float mu2s = m2 * m2;
            float m12  = m1 * m2;
            float num = (2.f * m12 + C1v) * (2.f * (spt[j] - m12) + C2v);
            float den = (mu1s + mu2s + C1v) * ((spp[j] - mu1s) + (stt[j] - mu2s) + C2v);
            ssim_acc += num * __builtin_amdgcn_rcpf(den);
        }
    }

    // ================= block reduction -> global double atomics =============
    #pragma unroll
    for (int off = 32; off > 0; off >>= 1) {
        ssim_acc += __shfl_down(ssim_acc, off, 64);
        l1_acc   += __shfl_down(l1_acc,   off, 64);
    }
    __shared__ float red[2][4];
    int lane = tid & 63;
    int wid  = tid >> 6;
    if (lane == 0) { red[0][wid] = ssim_acc; red[1][wid] = l1_acc; }
    __syncthreads();
    if (tid == 0) {
        float s = red[0][0] + red[0][1] + red[0][2] + red[0][3];
        float l = red[1][0] + red[1][1] + red[1][2] + red[1][3];
        atomicAdd(&acc[0], (double)s);
        atomicAdd(&acc[1], (double)l);
    }
}

__global__ void finalize_kernel(const double* __restrict__ acc,
                                float* __restrict__ out, double invN)
{
    double ssim_mean = acc[0] * invN;
    double l1_mean   = acc[1] * invN;
    out[0] = (float)(0.8 * l1_mean + 0.2 * (1.0 - ssim_mean));
}

extern "C" void kernel_launch(void* const* d_in, const int* in_sizes, int n_in,
                              void* d_out, int out_size, void* d_ws, size_t ws_size,
                              hipStream_t stream)
{
    const float* pred = (const float*)d_in[0];
    const float* targ = (const float*)d_in[1];
    float* out = (float*)d_out;
    double* acc = (double*)d_ws;

    const int C = 3, H = 2160, W = 3840;

    hipMemsetAsync(acc, 0, 2 * sizeof(double), stream);

    W11 wt;
    double g[WSZ], s = 0.0;
    for (int i = 0; i < WSZ; ++i) {
        double d = (double)i - (WSZ / 2);
        g[i] = exp(-(d * d) / (2.0 * 1.5 * 1.5));
        s += g[i];
    }
    for (int i = 0; i < WSZ; ++i) wt.w[i] = (float)(g[i] / s);

    dim3 grid(W / TX, H / TY, C);   // 120 x 90 x 3
    ssim_l1_kernel<<<grid, 256, 0, stream>>>(pred, targ, wt, acc);

    double invN = 1.0 / ((double)C * (double)H * (double)W);
    finalize_kernel<<<1, 1, 0, stream>>>(acc, out, invN);
}

// Round 7
// 369.502 us; speedup vs baseline: 2.7115x; 2.5310x over previous
//
#include <hip/hip_runtime.h>
#include <math.h>

#define WSZ 11
#define PAD 5
#define TX 32
#define TY 24
#define NY 6                 // y-tiles per block: 144 rows/block, 2160/144 = 15
#define IY (TY + 2*PAD)      // 34
#define RX 8
#define SSTR (TX + 2)        // 34: even (8B-aligned b64 writes)
#define RY 3                 // output rows per thread in v-pass (8 groups x 3 = 24)
#define SEG (RX + 2*PAD)     // 18 floats per h-pass thread segment

struct W11 { float w[WSZ]; };

// (256,4): proven no-spill point (VGPR~60-64). Duration law discovered R1-R6:
// dur ~= 26ns * #blocks regardless of per-block work -> per-block serialization
// (same-address double atomics / dispatch overhead). Fix: 6 tiles per block +
// contention-free partials instead of global atomics.
__global__ __launch_bounds__(256, 4) void ssim_l1_kernel(
    const float* __restrict__ pred, const float* __restrict__ targ,
    W11 wt, float2* __restrict__ partials)
{
    constexpr int H = 2160, W = 3840;
    __shared__ float sH[5][IY][SSTR];   // h-conv of p, t, p^2, t^2, p*t  (22.6 KB)

    const int c   = blockIdx.z;
    const int gx0 = blockIdx.x * TX;
    const size_t plane = (size_t)H * W;
    const float* p = pred + (size_t)c * plane;
    const float* t = targ + (size_t)c * plane;

    const int tid = threadIdx.x;
    float l1_acc = 0.f;
    float ssim_acc = 0.f;
    const float C1v = 0.0001f, C2v = 0.0009f;

    // Phase A thread mapping (constant across tiles)
    const int rA  = tid >> 2;          // row in [0, IY)
    const int lxA = tid & 3;           // x-chunk
    // Phase B thread mapping
    const int oxB  = tid & 31;
    const int oy0B = (tid >> 5) * RY;

    const bool xfast = (blockIdx.x >= 1) && (blockIdx.x <= (W / TX) - 2);

    for (int s = 0; s < NY; ++s) {
        const int gy0 = (blockIdx.y * NY + s) * TY;

        // ============ Phase A: horizontal 11-tap, global -> LDS ============
        if (rA < IY) {
            const int gy  = gy0 + rA - PAD;
            const int gxs = gx0 + lxA * RX - PAD;
            const bool rowok = (gy >= 0) && (gy < H);

            float pv[SEG], tv[SEG];
            if (rowok && xfast) {
                // gxs-3 = gx0 + lx*8 - 8 is 32B-aligned
                const float4* p4 = (const float4*)(p + (size_t)gy * W + (gxs - 3));
                const float4* t4 = (const float4*)(t + (size_t)gy * W + (gxs - 3));
                float pb[24], tb[24];
                #pragma unroll
                for (int i = 0; i < 6; ++i) {
                    float4 a = p4[i];
                    pb[4*i+0] = a.x; pb[4*i+1] = a.y; pb[4*i+2] = a.z; pb[4*i+3] = a.w;
                    float4 b = t4[i];
                    tb[4*i+0] = b.x; tb[4*i+1] = b.y; tb[4*i+2] = b.z; tb[4*i+3] = b.w;
                }
                #pragma unroll
                for (int e = 0; e < SEG; ++e) { pv[e] = pb[e+3]; tv[e] = tb[e+3]; }
            } else if (rowok) {
                const size_t rowoff = (size_t)gy * W;
                #pragma unroll
                for (int e = 0; e < SEG; ++e) {
                    int gx = gxs + e;
                    bool ok = (gx >= 0) && (gx < W);
                    pv[e] = ok ? p[rowoff + gx] : 0.f;
                    tv[e] = ok ? t[rowoff + gx] : 0.f;
                }
            } else {
                #pragma unroll
                for (int e = 0; e < SEG; ++e) { pv[e] = 0.f; tv[e] = 0.f; }
            }

            float hp[RX], ht[RX], hpp[RX], htt[RX], hpt[RX];
            #pragma unroll
            for (int j = 0; j < RX; ++j) {
                hp[j] = 0.f; ht[j] = 0.f; hpp[j] = 0.f; htt[j] = 0.f; hpt[j] = 0.f;
            }
            #pragma unroll
            for (int e = 0; e < SEG; ++e) {
                float pe = pv[e], te = tv[e];
                float pp = pe * pe, tt = te * te, pt = pe * te;
                #pragma unroll
                for (int j = 0; j < RX; ++j) {
                    int k = e - j;
                    if (k >= 0 && k < WSZ) {
                        float wv = wt.w[k];
                        hp[j]  += wv * pe;
                        ht[j]  += wv * te;
                        hpp[j] += wv * pp;
                        htt[j] += wv * tt;
                        hpt[j] += wv * pt;
                    }
                }
            }
            const int xb = lxA * RX;
            #pragma unroll
            for (int j = 0; j < RX; j += 2) {
                *(float2*)&sH[0][rA][xb + j] = make_float2(hp[j],  hp[j+1]);
                *(float2*)&sH[1][rA][xb + j] = make_float2(ht[j],  ht[j+1]);
                *(float2*)&sH[2][rA][xb + j] = make_float2(hpp[j], hpp[j+1]);
                *(float2*)&sH[3][rA][xb + j] = make_float2(htt[j], htt[j+1]);
                *(float2*)&sH[4][rA][xb + j] = make_float2(hpt[j], hpt[j+1]);
            }
            if (rA >= PAD && rA < PAD + TY) {
                #pragma unroll
                for (int e = PAD; e < PAD + RX; ++e)
                    l1_acc += fabsf(pv[e] - tv[e]);
            }
        }
        __syncthreads();

        // ============ Phase B: vertical 11-tap + SSIM ======================
        {
            float mu1[RY], mu2[RY], spp[RY], stt[RY], spt[RY];
            #pragma unroll
            for (int j = 0; j < RY; ++j) {
                mu1[j] = 0.f; mu2[j] = 0.f; spp[j] = 0.f; stt[j] = 0.f; spt[j] = 0.f;
            }
            #pragma unroll
            for (int k = 0; k < RY + 2 * PAD; ++k) {
                float a0 = sH[0][oy0B + k][oxB];
                float a1 = sH[1][oy0B + k][oxB];
                float a2 = sH[2][oy0B + k][oxB];
                float a3 = sH[3][oy0B + k][oxB];
                float a4 = sH[4][oy0B + k][oxB];
                #pragma unroll
                for (int j = 0; j < RY; ++j) {
                    int kk = k - j;
                    if (kk >= 0 && kk < WSZ) {
                        float wv = wt.w[kk];
                        mu1[j] += wv * a0;
                        mu2[j] += wv * a1;
                        spp[j] += wv * a2;
                        stt[j] += wv * a3;
                        spt[j] += wv * a4;
                    }
                }
            }
            #pragma unroll
            for (int j = 0; j < RY; ++j) {
                float m1 = mu1[j], m2 = mu2[j];
                float mu1s = m1 * m1;
                float mu2s = m2 * m2;
                float m12  = m1 * m2;
                float num = (2.f * m12 + C1v) * (2.f * (spt[j] - m12) + C2v);
                float den = (mu1s + mu2s + C1v) * ((spp[j] - mu1s) + (stt[j] - mu2s) + C2v);
                ssim_acc += num * __builtin_amdgcn_rcpf(den);
            }
        }
        __syncthreads();   // before next tile's Phase A overwrites sH
    }

    // ============ block reduction -> contention-free partial ================
    #pragma unroll
    for (int off = 32; off > 0; off >>= 1) {
        ssim_acc += __shfl_down(ssim_acc, off, 64);
        l1_acc   += __shfl_down(l1_acc,   off, 64);
    }
    __shared__ float red[2][4];
    int lane = tid & 63;
    int wid  = tid >> 6;
    if (lane == 0) { red[0][wid] = ssim_acc; red[1][wid] = l1_acc; }
    __syncthreads();
    if (tid == 0) {
        float sv = red[0][0] + red[0][1] + red[0][2] + red[0][3];
        float lv = red[1][0] + red[1][1] + red[1][2] + red[1][3];
        int bid = (blockIdx.z * gridDim.y + blockIdx.y) * gridDim.x + blockIdx.x;
        partials[bid] = make_float2(sv, lv);
    }
}

__global__ __launch_bounds__(256) void finalize_kernel(
    const float2* __restrict__ partials, int n,
    float* __restrict__ out, double invN)
{
    const int tid = threadIdx.x;
    double s = 0.0, l = 0.0;
    for (int i = tid; i < n; i += 256) {
        float2 v = partials[i];
        s += (double)v.x;
        l += (double)v.y;
    }
    #pragma unroll
    for (int off = 32; off > 0; off >>= 1) {
        s += __shfl_down(s, off, 64);
        l += __shfl_down(l, off, 64);
    }
    __shared__ double rs[4], rl[4];
    int lane = tid & 63, wid = tid >> 6;
    if (lane == 0) { rs[wid] = s; rl[wid] = l; }
    __syncthreads();
    if (tid == 0) {
        double st = rs[0] + rs[1] + rs[2] + rs[3];
        double lt = rl[0] + rl[1] + rl[2] + rl[3];
        out[0] = (float)(0.8 * lt * invN + 0.2 * (1.0 - st * invN));
    }
}

extern "C" void kernel_launch(void* const* d_in, const int* in_sizes, int n_in,
                              void* d_out, int out_size, void* d_ws, size_t ws_size,
                              hipStream_t stream)
{
    const float* pred = (const float*)d_in[0];
    const float* targ = (const float*)d_in[1];
    float* out = (float*)d_out;
    float2* partials = (float2*)d_ws;

    const int C = 3, H = 2160, W = 3840;

    W11 wt;
    double g[WSZ], sg = 0.0;
    for (int i = 0; i < WSZ; ++i) {
        double d = (double)i - (WSZ / 2);
        g[i] = exp(-(d * d) / (2.0 * 1.5 * 1.5));
        sg += g[i];
    }
    for (int i = 0; i < WSZ; ++i) wt.w[i] = (float)(g[i] / sg);

    dim3 grid(W / TX, H / (TY * NY), C);   // 120 x 15 x 3 = 5400 blocks
    ssim_l1_kernel<<<grid, 256, 0, stream>>>(pred, targ, wt, partials);

    const int nblocks = (W / TX) * (H / (TY * NY)) * C;
    double invN = 1.0 / ((double)C * (double)H * (double)W);
    finalize_kernel<<<1, 256, 0, stream>>>(partials, nblocks, out, invN);
}

// Round 8
// 315.439 us; speedup vs baseline: 3.1762x; 1.1714x over previous
//
#include <hip/hip_runtime.h>
#include <math.h>

#define WSZ 11
#define PAD 5
#define TX 32
#define TY 24
#define NY 6                 // y-tiles per block: 144 rows/block, 2160/144 = 15
#define IY (TY + 2*PAD)      // 34
#define RX 4                 // h-pass: 4 output px per task
#define NTASK (IY * 8)       // 272 tasks on 256 threads (tid<16 do 2)
#define SEG (RX + 2*PAD)     // 14 input floats per task
#define RY 3                 // v-pass rows per thread (8 groups x 3 = 24)
#define SA 33                // sHA row stride in float4 (odd -> rotating banks)
#define SB 35                // sHB row stride in float (odd)

struct W11 { float w[WSZ]; };

// Macro-structure from R7 (5400 blocks, contention-free partials) — the
// per-block serialization fix that took 794->245us. R8: full-thread Phase A
// (272-task loop), register-only staging (R7 spilled 146MB scratch), and
// interleaved LDS (float4{p,t,pp,tt} + float{pt}) cutting Phase B LDS reads
// 80 -> 32 per thread.
__global__ __launch_bounds__(256, 4) void ssim_l1_kernel(
    const float* __restrict__ pred, const float* __restrict__ targ,
    W11 wt, float2* __restrict__ partials)
{
    constexpr int H = 2160, W = 3840;
    __shared__ float4 sHA[IY][SA];   // {hp, ht, hpp, htt}   17.4 KB
    __shared__ float  sHB[IY][SB];   // hpt                   4.8 KB

    const int c   = blockIdx.z;
    const int gx0 = blockIdx.x * TX;
    const size_t plane = (size_t)H * W;
    const float* p = pred + (size_t)c * plane;
    const float* t = targ + (size_t)c * plane;

    const int tid = threadIdx.x;
    float l1_acc = 0.f;
    float ssim_acc = 0.f;
    const float C1v = 0.0001f, C2v = 0.0009f;

    const int oxB  = tid & 31;
    const int oy0B = (tid >> 5) * RY;
    const bool xfast = (blockIdx.x >= 1) && (blockIdx.x <= (W / TX) - 2);

    for (int s = 0; s < NY; ++s) {
        const int gy0 = (blockIdx.y * NY + s) * TY;

        // ============ Phase A: horizontal 11-tap, global -> LDS ============
        for (int task = tid; task < NTASK; task += 256) {
            const int r  = task >> 3;
            const int cx = task & 7;
            const int gy  = gy0 + r - PAD;
            const int gxs = gx0 + cx * RX - PAD;   // input window e=0..13 -> gxs..gxs+13
            const bool rowok = (gy >= 0) && (gy < H);

            // 5 aligned float4 per image covering gxs-3 .. gxs+16 (registers only)
            float4 P[5], T[5];
            if (rowok && xfast) {
                const float4* p4 = (const float4*)(p + (size_t)gy * W + (gxs - 3));
                const float4* t4 = (const float4*)(t + (size_t)gy * W + (gxs - 3));
                #pragma unroll
                for (int i = 0; i < 5; ++i) { P[i] = p4[i]; T[i] = t4[i]; }
            } else if (rowok) {
                const size_t rowoff = (size_t)gy * W;
                #pragma unroll
                for (int i = 0; i < 5; ++i) {
                    float pe[4], te[4];
                    #pragma unroll
                    for (int q = 0; q < 4; ++q) {
                        int gx = gxs - 3 + 4 * i + q;
                        bool ok = (gx >= 0) && (gx < W);
                        pe[q] = ok ? p[rowoff + gx] : 0.f;
                        te[q] = ok ? t[rowoff + gx] : 0.f;
                    }
                    P[i] = make_float4(pe[0], pe[1], pe[2], pe[3]);
                    T[i] = make_float4(te[0], te[1], te[2], te[3]);
                }
            } else {
                #pragma unroll
                for (int i = 0; i < 5; ++i) {
                    P[i] = make_float4(0.f, 0.f, 0.f, 0.f);
                    T[i] = make_float4(0.f, 0.f, 0.f, 0.f);
                }
            }

            float hp[RX], ht[RX], hpp[RX], htt[RX], hpt[RX];
            #pragma unroll
            for (int j = 0; j < RX; ++j) {
                hp[j] = 0.f; ht[j] = 0.f; hpp[j] = 0.f; htt[j] = 0.f; hpt[j] = 0.f;
            }
            #pragma unroll
            for (int e = 0; e < SEG; ++e) {
                // element e of the window = component (e+3) of the float4 run
                const int ii = (e + 3) >> 2, qq = (e + 3) & 3;
                const float pe = (qq == 0) ? P[ii].x : (qq == 1) ? P[ii].y
                                : (qq == 2) ? P[ii].z : P[ii].w;
                const float te = (qq == 0) ? T[ii].x : (qq == 1) ? T[ii].y
                                : (qq == 2) ? T[ii].z : T[ii].w;
                const float pp = pe * pe, tt = te * te, pt = pe * te;
                #pragma unroll
                for (int j = 0; j < RX; ++j) {
                    const int k = e - j;
                    if (k >= 0 && k < WSZ) {
                        const float wv = wt.w[k];
                        hp[j]  += wv * pe;
                        ht[j]  += wv * te;
                        hpp[j] += wv * pp;
                        htt[j] += wv * tt;
                        hpt[j] += wv * pt;
                    }
                }
                // L1 on owned pixels (e = 5..8 <-> gx = gx0+cx*4 .. +3), once per pixel
                if (e >= PAD && e < PAD + RX && r >= PAD && r < PAD + TY)
                    l1_acc += fabsf(pe - te);
            }
            const int xb = cx * RX;
            #pragma unroll
            for (int j = 0; j < RX; ++j) {
                sHA[r][xb + j] = make_float4(hp[j], ht[j], hpp[j], htt[j]);
                sHB[r][xb + j] = hpt[j];
            }
        }
        __syncthreads();

        // ============ Phase B: vertical 11-tap + SSIM ======================
        {
            float mu1[RY], mu2[RY], spp[RY], stt[RY], spt[RY];
            #pragma unroll
            for (int j = 0; j < RY; ++j) {
                mu1[j] = 0.f; mu2[j] = 0.f; spp[j] = 0.f; stt[j] = 0.f; spt[j] = 0.f;
            }
            #pragma unroll
            for (int k = 0; k < RY + 2 * PAD; ++k) {
                const float4 f = sHA[oy0B + k][oxB];
                const float  g = sHB[oy0B + k][oxB];
                #pragma unroll
                for (int j = 0; j < RY; ++j) {
                    const int kk = k - j;
                    if (kk >= 0 && kk < WSZ) {
                        const float wv = wt.w[kk];
                        mu1[j] += wv * f.x;
                        mu2[j] += wv * f.y;
                        spp[j] += wv * f.z;
                        stt[j] += wv * f.w;
                        spt[j] += wv * g;
                    }
                }
            }
            #pragma unroll
            for (int j = 0; j < RY; ++j) {
                const float m1 = mu1[j], m2 = mu2[j];
                const float mu1s = m1 * m1;
                const float mu2s = m2 * m2;
                const float m12  = m1 * m2;
                const float num = (2.f * m12 + C1v) * (2.f * (spt[j] - m12) + C2v);
                const float den = (mu1s + mu2s + C1v) * ((spp[j] - mu1s) + (stt[j] - mu2s) + C2v);
                ssim_acc += num * __builtin_amdgcn_rcpf(den);
            }
        }
        __syncthreads();   // before next tile's Phase A overwrites LDS
    }

    // ============ block reduction -> contention-free partial ================
    #pragma unroll
    for (int off = 32; off > 0; off >>= 1) {
        ssim_acc += __shfl_down(ssim_acc, off, 64);
        l1_acc   += __shfl_down(l1_acc,   off, 64);
    }
    __shared__ float red[2][4];
    const int lane = tid & 63;
    const int wid  = tid >> 6;
    if (lane == 0) { red[0][wid] = ssim_acc; red[1][wid] = l1_acc; }
    __syncthreads();
    if (tid == 0) {
        const float sv = red[0][0] + red[0][1] + red[0][2] + red[0][3];
        const float lv = red[1][0] + red[1][1] + red[1][2] + red[1][3];
        const int bid = (blockIdx.z * gridDim.y + blockIdx.y) * gridDim.x + blockIdx.x;
        partials[bid] = make_float2(sv, lv);
    }
}

__global__ __launch_bounds__(256) void finalize_kernel(
    const float2* __restrict__ partials, int n,
    float* __restrict__ out, double invN)
{
    const int tid = threadIdx.x;
    double s = 0.0, l = 0.0;
    for (int i = tid; i < n; i += 256) {
        float2 v = partials[i];
        s += (double)v.x;
        l += (double)v.y;
    }
    #pragma unroll
    for (int off = 32; off > 0; off >>= 1) {
        s += __shfl_down(s, off, 64);
        l += __shfl_down(l, off, 64);
    }
    __shared__ double rs[4], rl[4];
    const int lane = tid & 63, wid = tid >> 6;
    if (lane == 0) { rs[wid] = s; rl[wid] = l; }
    __syncthreads();
    if (tid == 0) {
        const double st = rs[0] + rs[1] + rs[2] + rs[3];
        const double lt = rl[0] + rl[1] + rl[2] + rl[3];
        out[0] = (float)(0.8 * lt * invN + 0.2 * (1.0 - st * invN));
    }
}

extern "C" void kernel_launch(void* const* d_in, const int* in_sizes, int n_in,
                              void* d_out, int out_size, void* d_ws, size_t ws_size,
                              hipStream_t stream)
{
    const float* pred = (const float*)d_in[0];
    const float* targ = (const float*)d_in[1];
    float* out = (float*)d_out;
    float2* partials = (float2*)d_ws;

    const int C = 3, H = 2160, W = 3840;

    W11 wt;
    double g[WSZ], sg = 0.0;
    for (int i = 0; i < WSZ; ++i) {
        double d = (double)i - (WSZ / 2);
        g[i] = exp(-(d * d) / (2.0 * 1.5 * 1.5));
        sg += g[i];
    }
    for (int i = 0; i < WSZ; ++i) wt.w[i] = (float)(g[i] / sg);

    dim3 grid(W / TX, H / (TY * NY), C);   // 120 x 15 x 3 = 5400 blocks
    ssim_l1_kernel<<<grid, 256, 0, stream>>>(pred, targ, wt, partials);

    const int nblocks = (W / TX) * (H / (TY * NY)) * C;
    double invN = 1.0 / ((double)C * (double)H * (double)W);
    finalize_kernel<<<1, 256, 0, stream>>>(partials, nblocks, out, invN);
}

// Round 9
// 312.369 us; speedup vs baseline: 3.2074x; 1.0098x over previous
//
#include <hip/hip_runtime.h>
#include <math.h>

#define WSZ 11
#define PAD 5
#define TX 32
#define TY 24
#define NY 6                 // y-tiles per block: 144 rows/block, 2160/144 = 15
#define IY (TY + 2*PAD)      // 34
#define RX 4                 // h-pass: 4 output px per task
#define NTASK (IY * 8)       // 272 tasks on 256 threads (tid<16 do 2)
#define SEG (RX + 2*PAD)     // 14 input floats per task
#define RY 3                 // v-pass rows per thread (8 groups x 3 = 24)
#define SA 33                // sHA row stride in float4 (odd -> rotating banks)
#define SB 35                // sHB row stride in float (odd)

typedef float v2f __attribute__((ext_vector_type(2)));

struct W11 { float w[WSZ]; };

// R7 macro-structure (5400 blocks, contention-free partials; per-block
// serialization fix 794->245us) + R8 full-thread Phase A / register staging /
// interleaved LDS (245->190us, VALUBusy 81%). R9: packed-f32 math — all conv
// FMAs paired as ext_vector_type(2) so the backend emits v_pk_fma_f32:
// (hp,ht),(hpp,htt) share weight+pixel pair; Phase B (mu1,mu2),(spp,stt)
// load adjacent float4 components. 5 issues/(tap,out) -> 3.
__global__ __launch_bounds__(256, 4) void ssim_l1_kernel(
    const float* __restrict__ pred, const float* __restrict__ targ,
    W11 wt, float2* __restrict__ partials)
{
    constexpr int H = 2160, W = 3840;
    __shared__ float4 sHA[IY][SA];   // {hp, ht, hpp, htt}   17.4 KB
    __shared__ float  sHB[IY][SB];   // hpt                   4.8 KB

    const int c   = blockIdx.z;
    const int gx0 = blockIdx.x * TX;
    const size_t plane = (size_t)H * W;
    const float* p = pred + (size_t)c * plane;
    const float* t = targ + (size_t)c * plane;

    const int tid = threadIdx.x;
    v2f loss_acc = {0.f, 0.f};       // .x = ssim, .y = l1
    const float C1v = 0.0001f, C2v = 0.0009f;

    const int oxB  = tid & 31;
    const int oy0B = (tid >> 5) * RY;
    const bool xfast = (blockIdx.x >= 1) && (blockIdx.x <= (W / TX) - 2);

    for (int s = 0; s < NY; ++s) {
        const int gy0 = (blockIdx.y * NY + s) * TY;

        // ============ Phase A: horizontal 11-tap, global -> LDS ============
        for (int task = tid; task < NTASK; task += 256) {
            const int r  = task >> 3;
            const int cx = task & 7;
            const int gy  = gy0 + r - PAD;
            const int gxs = gx0 + cx * RX - PAD;   // input window e=0..13
            const bool rowok = (gy >= 0) && (gy < H);

            // 5 aligned float4 per image covering gxs-3 .. gxs+16 (registers only)
            float4 P[5], T[5];
            if (rowok && xfast) {
                const float4* p4 = (const float4*)(p + (size_t)gy * W + (gxs - 3));
                const float4* t4 = (const float4*)(t + (size_t)gy * W + (gxs - 3));
                #pragma unroll
                for (int i = 0; i < 5; ++i) { P[i] = p4[i]; T[i] = t4[i]; }
            } else if (rowok) {
                const size_t rowoff = (size_t)gy * W;
                #pragma unroll
                for (int i = 0; i < 5; ++i) {
                    float pe[4], te[4];
                    #pragma unroll
                    for (int q = 0; q < 4; ++q) {
                        int gx = gxs - 3 + 4 * i + q;
                        bool ok = (gx >= 0) && (gx < W);
                        pe[q] = ok ? p[rowoff + gx] : 0.f;
                        te[q] = ok ? t[rowoff + gx] : 0.f;
                    }
                    P[i] = make_float4(pe[0], pe[1], pe[2], pe[3]);
                    T[i] = make_float4(te[0], te[1], te[2], te[3]);
                }
            } else {
                #pragma unroll
                for (int i = 0; i < 5; ++i) {
                    P[i] = make_float4(0.f, 0.f, 0.f, 0.f);
                    T[i] = make_float4(0.f, 0.f, 0.f, 0.f);
                }
            }

            v2f h_ab[RX], h_sq[RX];
            float h_pt[RX];
            #pragma unroll
            for (int j = 0; j < RX; ++j) {
                h_ab[j] = (v2f){0.f, 0.f};
                h_sq[j] = (v2f){0.f, 0.f};
                h_pt[j] = 0.f;
            }
            #pragma unroll
            for (int e = 0; e < SEG; ++e) {
                const int ii = (e + 3) >> 2, qq = (e + 3) & 3;
                const float pe = (qq == 0) ? P[ii].x : (qq == 1) ? P[ii].y
                                : (qq == 2) ? P[ii].z : P[ii].w;
                const float te = (qq == 0) ? T[ii].x : (qq == 1) ? T[ii].y
                                : (qq == 2) ? T[ii].z : T[ii].w;
                v2f vab; vab.x = pe; vab.y = te;
                const v2f vsq = vab * vab;          // v_pk_mul_f32
                const float pt = pe * te;
                #pragma unroll
                for (int j = 0; j < RX; ++j) {
                    const int k = e - j;
                    if (k >= 0 && k < WSZ) {
                        const float wv = wt.w[k];
                        h_ab[j] += wv * vab;        // v_pk_fma_f32
                        h_sq[j] += wv * vsq;        // v_pk_fma_f32
                        h_pt[j] += wv * pt;
                    }
                }
                // L1 on owned pixels (each counted exactly once across tasks)
                if (e >= PAD && e < PAD + RX && r >= PAD && r < PAD + TY)
                    loss_acc.y += fabsf(pe - te);
            }
            const int xb = cx * RX;
            #pragma unroll
            for (int j = 0; j < RX; ++j) {
                sHA[r][xb + j] = make_float4(h_ab[j].x, h_ab[j].y,
                                             h_sq[j].x, h_sq[j].y);
                sHB[r][xb + j] = h_pt[j];
            }
        }
        __syncthreads();

        // ============ Phase B: vertical 11-tap + SSIM ======================
        {
            v2f mu[RY], sq[RY];
            float sp[RY];
            #pragma unroll
            for (int j = 0; j < RY; ++j) {
                mu[j] = (v2f){0.f, 0.f};
                sq[j] = (v2f){0.f, 0.f};
                sp[j] = 0.f;
            }
            #pragma unroll
            for (int k = 0; k < RY + 2 * PAD; ++k) {
                const float4 f = sHA[oy0B + k][oxB];
                const float  g = sHB[oy0B + k][oxB];
                v2f fab; fab.x = f.x; fab.y = f.y;
                v2f fsq; fsq.x = f.z; fsq.y = f.w;
                #pragma unroll
                for (int j = 0; j < RY; ++j) {
                    const int kk = k - j;
                    if (kk >= 0 && kk < WSZ) {
                        const float wv = wt.w[kk];
                        mu[j] += wv * fab;          // v_pk_fma_f32
                        sq[j] += wv * fsq;          // v_pk_fma_f32
                        sp[j] += wv * g;
                    }
                }
            }
            #pragma unroll
            for (int j = 0; j < RY; ++j) {
                const float m1 = mu[j].x, m2 = mu[j].y;
                const float mu1s = m1 * m1;
                const float mu2s = m2 * m2;
                const float m12  = m1 * m2;
                const float num = (2.f * m12 + C1v) * (2.f * (sp[j] - m12) + C2v);
                const float den = (mu1s + mu2s + C1v)
                                * ((sq[j].x - mu1s) + (sq[j].y - mu2s) + C2v);
                loss_acc.x += num * __builtin_amdgcn_rcpf(den);
            }
        }
        __syncthreads();   // before next tile's Phase A overwrites LDS
    }

    // ============ block reduction -> contention-free partial ================
    #pragma unroll
    for (int off = 32; off > 0; off >>= 1) {
        loss_acc.x += __shfl_down(loss_acc.x, off, 64);
        loss_acc.y += __shfl_down(loss_acc.y, off, 64);
    }
    __shared__ float red[2][4];
    const int lane = tid & 63;
    const int wid  = tid >> 6;
    if (lane == 0) { red[0][wid] = loss_acc.x; red[1][wid] = loss_acc.y; }
    __syncthreads();
    if (tid == 0) {
        const float sv = red[0][0] + red[0][1] + red[0][2] + red[0][3];
        const float lv = red[1][0] + red[1][1] + red[1][2] + red[1][3];
        const int bid = (blockIdx.z * gridDim.y + blockIdx.y) * gridDim.x + blockIdx.x;
        partials[bid] = make_float2(sv, lv);
    }
}

__global__ __launch_bounds__(256) void finalize_kernel(
    const float2* __restrict__ partials, int n,
    float* __restrict__ out, double invN)
{
    const int tid = threadIdx.x;
    double s = 0.0, l = 0.0;
    for (int i = tid; i < n; i += 256) {
        float2 v = partials[i];
        s += (double)v.x;
        l += (double)v.y;
    }
    #pragma unroll
    for (int off = 32; off > 0; off >>= 1) {
        s += __shfl_down(s, off, 64);
        l += __shfl_down(l, off, 64);
    }
    __shared__ double rs[4], rl[4];
    const int lane = tid & 63, wid = tid >> 6;
    if (lane == 0) { rs[wid] = s; rl[wid] = l; }
    __syncthreads();
    if (tid == 0) {
        const double st = rs[0] + rs[1] + rs[2] + rs[3];
        const double lt = rl[0] + rl[1] + rl[2] + rl[3];
        out[0] = (float)(0.8 * lt * invN + 0.2 * (1.0 - st * invN));
    }
}

extern "C" void kernel_launch(void* const* d_in, const int* in_sizes, int n_in,
                              void* d_out, int out_size, void* d_ws, size_t ws_size,
                              hipStream_t stream)
{
    const float* pred = (const float*)d_in[0];
    const float* targ = (const float*)d_in[1];
    float* out = (float*)d_out;
    float2* partials = (float2*)d_ws;

    const int C = 3, H = 2160, W = 3840;

    W11 wt;
    double g[WSZ], sg = 0.0;
    for (int i = 0; i < WSZ; ++i) {
        double d = (double)i - (WSZ / 2);
        g[i] = exp(-(d * d) / (2.0 * 1.5 * 1.5));
        sg += g[i];
    }
    for (int i = 0; i < WSZ; ++i) wt.w[i] = (float)(g[i] / sg);

    dim3 grid(W / TX, H / (TY * NY), C);   // 120 x 15 x 3 = 5400 blocks
    ssim_l1_kernel<<<grid, 256, 0, stream>>>(pred, targ, wt, partials);

    const int nblocks = (W / TX) * (H / (TY * NY)) * C;
    double invN = 1.0 / ((double)C * (double)H * (double)W);
    finalize_kernel<<<1, 256, 0, stream>>>(partials, nblocks, out, invN);
}